// Round 1
// baseline (1040.839 us; speedup 1.0000x reference)
//
#include <hip/hip_runtime.h>

#define N_ 32
#define C_ 512
#define T_ 2048
#define K_ 1024

#define TQ 128   // t-tile per block
#define KC 128   // k-chunk
#define CH 16    // c-chunk staged in LDS

// Kernel A: codebook squared norms into ws, and zero the two scalar outputs.
__global__ void knorm_init_kernel(const float* __restrict__ cb,
                                  float* __restrict__ knorm,
                                  float* __restrict__ out) {
    const int k = blockIdx.x;       // 1024 blocks
    const int lane = threadIdx.x;   // 64 threads = 1 wave
    const float* row = cb + (size_t)k * C_;
    float s = 0.f;
#pragma unroll
    for (int j = 0; j < C_ / 64; ++j) {
        float v = row[lane + 64 * j];
        s += v * v;
    }
#pragma unroll
    for (int off = 32; off > 0; off >>= 1) s += __shfl_down(s, off, 64);
    if (lane == 0) knorm[k] = s;
    if (k == 0 && lane == 0) {
        out[(size_t)N_ * C_ * T_ + 0] = 0.f;  // commit_loss
        out[(size_t)N_ * C_ * T_ + 1] = 0.f;  // perplexity
    }
}

// Kernel B: fused distance-GEMM + argmin + gather.
// Block: 256 threads as 16x16 (tx over k, ty over t), 8x8 acc/thread.
// score(t,k) = ||k||^2 - 2 * dot(x_t, cb_k)   (||x||^2 constant per t -> argmin-equivalent)
__global__ void __launch_bounds__(256)
vq_kernel(const float* __restrict__ x, const float* __restrict__ cb,
          const float* __restrict__ knorm, float* __restrict__ out) {
    __shared__ float smem[4416];
    float* Xs  = smem;                    // [CH][128]      2048 floats
    float* Bs  = smem + 2048;             // [CH][132] pad  2112 floats
    float* kns = smem + 4160;             // [KC]
    int*   idxs = (int*)(smem + 4288);    // [TQ]
    float* redv = smem;                   // [TQ][16]  (aliases Xs after compute)
    int*   redk = (int*)(smem + 2048);    // [TQ][16]  (aliases Bs after compute)

    const int tid = threadIdx.x;
    const int tx = tid & 15;
    const int ty = tid >> 4;
    const int b = blockIdx.x;
    const int n = b >> 4;                 // 16 blocks per n  (T/TQ = 16)
    const int t0 = (b & 15) * TQ;
    const float* xbase = x + (size_t)n * C_ * T_ + t0;

    float best[8];
    int bestk[8];
#pragma unroll
    for (int i = 0; i < 8; ++i) { best[i] = 3.4e38f; bestk[i] = 0; }

    for (int k0 = 0; k0 < K_; k0 += KC) {
        if (tid < KC) kns[tid] = knorm[k0 + tid];
        float acc[8][8];
#pragma unroll
        for (int i = 0; i < 8; ++i)
#pragma unroll
            for (int j = 0; j < 8; ++j) acc[i][j] = 0.f;

        for (int cc = 0; cc < C_; cc += CH) {
            __syncthreads();
            // stage X chunk: Xs[c][t] = x[n][cc+c][t0+t], float4 coalesced
#pragma unroll
            for (int j = 0; j < 2; ++j) {
                int f = tid + 256 * j;            // 0..511 float4s
                int cl = f >> 5;                  // 0..15
                int t4 = (f & 31) * 4;            // 0..124
                float4 v = *(const float4*)(xbase + (size_t)(cc + cl) * T_ + t4);
                *(float4*)&Xs[cl * 128 + t4] = v;
            }
            // stage B chunk transposed: Bs[c][k] = cb[k0+k][cc+c]
#pragma unroll
            for (int j = 0; j < 2; ++j) {
                int f = tid + 256 * j;            // 0..511
                int kl = f >> 2;                  // 0..127
                int c4 = (f & 3) * 4;             // 0,4,8,12
                float4 v = *(const float4*)(cb + (size_t)(k0 + kl) * C_ + cc + c4);
                Bs[(c4 + 0) * 132 + kl] = v.x;
                Bs[(c4 + 1) * 132 + kl] = v.y;
                Bs[(c4 + 2) * 132 + kl] = v.z;
                Bs[(c4 + 3) * 132 + kl] = v.w;
            }
            __syncthreads();
#pragma unroll
            for (int c = 0; c < CH; ++c) {
                float4 xa  = *(const float4*)&Xs[c * 128 + ty * 8];
                float4 xb2 = *(const float4*)&Xs[c * 128 + ty * 8 + 4];
                float4 ba  = *(const float4*)&Bs[c * 132 + tx * 8];
                float4 bb  = *(const float4*)&Bs[c * 132 + tx * 8 + 4];
                float xr[8] = {xa.x, xa.y, xa.z, xa.w, xb2.x, xb2.y, xb2.z, xb2.w};
                float br[8] = {ba.x, ba.y, ba.z, ba.w, bb.x, bb.y, bb.z, bb.w};
#pragma unroll
                for (int i = 0; i < 8; ++i)
#pragma unroll
                    for (int j = 0; j < 8; ++j)
                        acc[i][j] = fmaf(xr[i], br[j], acc[i][j]);
            }
        }
        // epilogue: scores + running argmin (k ascending -> strict < keeps first min)
#pragma unroll
        for (int j = 0; j < 8; ++j) {
            const int kk = k0 + tx * 8 + j;
            const float kn = kns[tx * 8 + j];
#pragma unroll
            for (int i = 0; i < 8; ++i) {
                float s = fmaf(-2.f, acc[i][j], kn);
                if (s < best[i]) { best[i] = s; bestk[i] = kk; }
            }
        }
        __syncthreads();
    }

    // cross-thread argmin reduce: 16 partials per t row
#pragma unroll
    for (int i = 0; i < 8; ++i) {
        redv[(ty * 8 + i) * 16 + tx] = best[i];
        redk[(ty * 8 + i) * 16 + tx] = bestk[i];
    }
    __syncthreads();
    if (tid < TQ) {
        float bv = redv[tid * 16];
        int bk = redk[tid * 16];
#pragma unroll
        for (int j = 1; j < 16; ++j) {
            float v = redv[tid * 16 + j];
            int kj = redk[tid * 16 + j];
            if (v < bv || (v == bv && kj < bk)) { bv = v; bk = kj; }
        }
        idxs[tid] = bk;  // numpy argmin tie-break: smallest index
    }
    __syncthreads();

    // gather epilogue: out[n][c][t0+t] = cb[idxs[t]][c], float4 stores over t
    const int tg = (tid & 31) * 4;   // t 0..124 step 4
    const int cs = tid >> 5;         // 0..7
    const float* r0 = cb + (size_t)idxs[tg + 0] * C_;
    const float* r1 = cb + (size_t)idxs[tg + 1] * C_;
    const float* r2 = cb + (size_t)idxs[tg + 2] * C_;
    const float* r3 = cb + (size_t)idxs[tg + 3] * C_;
    float* obase = out + (size_t)n * C_ * T_ + t0 + tg;
    for (int c = cs; c < C_; c += 8) {
        float4 v;
        v.x = r0[c]; v.y = r1[c]; v.z = r2[c]; v.w = r3[c];
        *(float4*)&obase[(size_t)c * T_] = v;
    }
}

extern "C" void kernel_launch(void* const* d_in, const int* in_sizes, int n_in,
                              void* d_out, int out_size, void* d_ws, size_t ws_size,
                              hipStream_t stream) {
    const float* x  = (const float*)d_in[0];   // [32,512,2048] fp32
    const float* cb = (const float*)d_in[1];   // [1024,512] fp32
    float* out = (float*)d_out;                // 32*512*2048 + 2 floats
    float* knorm = (float*)d_ws;               // 4 KB scratch
    knorm_init_kernel<<<K_, 64, 0, stream>>>(cb, knorm, out);
    vq_kernel<<<(N_ * T_) / TQ, 256, 0, stream>>>(x, cb, knorm, out);
}